// Round 7
// baseline (194.092 us; speedup 1.0000x reference)
//
#include <hip/hip_runtime.h>

// LatticeFilter: step-up (Levinson-Durbin) recursion, rc -> LPC coeffs.
//   rc: (B=16, p=128, Tf=8192) fp32, k_i = 0.98*rc[b,i,t]
//   out: (B, Tf, p+1=129) fp32, a[...,0]=1
//
// R12. Allocator rule reverse-engineered from R5..R11:
//   amdgpu_waves_per_eu is IGNORED. The compile-time register budget is
//   steered by STATIC LDS size: >=33KB -> 4 blocks/CU -> with 64-thread
//   blocks that's 1 wave/EU -> budget >=256 (R6: VGPR=132 clean, R7: 148).
//   LDS=0 -> allocator targets 8 waves/EU -> VGPR 60..88 -> scratch spill
//   (R9-A, R11-A/B: 90us, WRITE inflated by spill traffic).
// Front-end model (R5/R8/R10): straight-line text > L1I streams serially
// at ~130cy/64B line regardless of occupancy/lockstep; text <= 13KB (R8-A)
// runs at the BW floor. => both split halves must fit ~32KB.
//
// R12 = R11's split (S=90, v_fmac VOP2 12B/pair, state parked in final out
// slots, bit-identical math) with the ALLOCATOR config fixed:
//   - BOTH kernels: 64-thread blocks (R6's proven path)
//   - A: 40KB static dummy LDS (kept alive via guarded use) -> 4 blk/CU
//   - B: real 33KB transpose LDS (R6's exact epilogue)
// Issue floors at 1 wave/SIMD: A ~11us < 15us BW floor, B ~11.3us < 21.4us
// BW floor -> both memory-bound; 2 generations cover load latency.
// Predict: A 14-18us VGPR~110-140, B 22-28us VGPR~130-150, WRITE exact
// (no spill), FETCH partially L3-absorbed.

#define NB    16
#define ORD   128
#define TF    8192
#define SPLIT 90

// ---- pair update j <-> m-j, VOP2 v_fmac encoding (4B vs VOP3 fma 8B) ----
// a[J] += k*a[M-J];  a[M-J] += k*a[J]_old   (old copy = 1 v_mov, 4B)
template<int M, int J>
struct PairUpd {
    static __device__ __forceinline__ void run(float (&a)[ORD + 1], float k) {
        const float lo = a[J];                  // old value (one v_mov)
        asm("v_fmac_f32 %0, %1, %2" : "+v"(a[J])     : "v"(k), "v"(a[M - J]));
        asm("v_fmac_f32 %0, %1, %2" : "+v"(a[M - J]) : "v"(k), "v"(lo));
        if constexpr (2 * (J + 1) < M) PairUpd<M, J + 1>::run(a, k);
    }
};

// Steps M..MEND; k from kq[M-1-K0]
template<int M, int MEND, int K0, int NK>
struct Step {
    static __device__ __forceinline__ void run(float (&a)[ORD + 1],
                                               const float (&kq)[NK]) {
        const float k = 0.98f * kq[M - 1 - K0];
        if constexpr (M > 2) PairUpd<M, 1>::run(a, k);
        if constexpr ((M & 1) == 0) {            // middle: a[M/2] += k*a[M/2]
            const float mid = a[M / 2];
            asm("v_fmac_f32 %0, %1, %2" : "+v"(a[M / 2]) : "v"(k), "v"(mid));
        }
        a[M] = k;                                // a[0] == 1 contributes k
        if constexpr (M < MEND) Step<M + 1, MEND, K0, NK>::run(a, kq);
    }
};

// ---- LDS staging, static indices (compiler merges into ds_write_b128) ----
template<int J>
struct Stage {
    static __device__ __forceinline__ void run(float* __restrict__ dst,
                                               const float (&a)[ORD + 1]) {
        dst[J] = a[J];
        if constexpr (J < ORD) Stage<J + 1>::run(dst, a);
    }
};

// =======================  Kernel A: steps 1..SPLIT  =======================
// ~28KB text < L1I. Writes a[1..SPLIT] to out[col*129+j] (final slots;
// 516B-strided dwords, L2 write-combines within the block footprint --
// proven at BW floor in R8-A).
__global__ __launch_bounds__(64)
void lpc_stepA(const float* __restrict__ rc, float* __restrict__ out) {
    // 40KB static LDS: occupancy governor (4 blocks/CU -> 1 wave/EU ->
    // full register budget). Kept alive by a ds_write + guarded read.
    __shared__ float lds_gov[64 * 160];

    const int lane = threadIdx.x;                     // 0..63, one wave
    const int col = blockIdx.x * 64 + lane;           // flattened (B*Tf) column
    const int b = col >> 13;
    const int t = col & (TF - 1);
    const float* rcp = rc + ((size_t)b * ORD) * TF + t;

    float kq[SPLIT];                                  // full prefetch: pressure
#pragma unroll                                        // flat (kq dies as a grows)
    for (int i = 0; i < SPLIT; ++i) kq[i] = rcp[(size_t)i * TF];

    float a[ORD + 1];
    a[0] = 1.0f;
    Step<1, SPLIT, 0, SPLIT>::run(a, kq);

    // keep the governor allocation alive (unprovable-but-never-taken read)
    lds_gov[lane] = a[SPLIT];
    __syncthreads();
    if (blockIdx.x == 0xFFFFFFFFu)                    // never true, unprovable
        out[0] = lds_gov[63 - lane];

    // state -> final out positions; strided dwords (L2 aggregates lines)
    float* op = out + (size_t)col * (ORD + 1);
#pragma unroll
    for (int j = 1; j <= SPLIT; ++j) op[j] = a[j];
}

// =====================  Kernel B: steps SPLIT+1..128  =====================
// ~26KB text < L1I. Reads state back, finishes, writes full rows via the
// proven conflict-free LDS transpose (stride 129 -> bank stride 1).
__global__ __launch_bounds__(64)
void lpc_stepB(const float* __restrict__ rc, float* out) {
    const int lane = threadIdx.x;                     // 0..63, one wave
    const int col = blockIdx.x * 64 + lane;
    const int b = col >> 13;
    const int t = col & (TF - 1);
    const float* rcp = rc + ((size_t)b * ORD) * TF + t;

    constexpr int NK = ORD - SPLIT;                   // 38 remaining k's
    float kq[NK];
#pragma unroll
    for (int i = 0; i < NK; ++i) kq[i] = rcp[(size_t)(SPLIT + i) * TF];

    float a[ORD + 1];
    a[0] = 1.0f;
    {   // reload state from final out positions (per-lane strided dwords;
        // consecutive j covers lines densely -> reads stay dense in L2/L3)
        const float* op = out + (size_t)col * (ORD + 1);
#pragma unroll
        for (int j = 1; j <= SPLIT; ++j) a[j] = op[j];
    }

    Step<SPLIT + 1, ORD, SPLIT, NK>::run(a, kq);

    // ---- epilogue: transpose 64 rows x 129 cols through LDS, 1 round ----
    // stage: bank stride 1 (129 mod 32 = 1) -> free 2-way wave64 aliasing
    // store: 2064 contiguous float4 -> every 128B line written whole
    // 33,024B LDS doubles as the occupancy governor (4 blk/CU, 1 wave/EU).
    __shared__ __align__(16) float lds[64 * (ORD + 1)];
    Stage<0>::run(&lds[lane * (ORD + 1)], a);
    __syncthreads();

    const float4* lds4 = (const float4*)lds;
    float4* out4 = (float4*)(out + (size_t)blockIdx.x * 64 * (ORD + 1));
#pragma unroll 4
    for (int e = lane; e < (64 * (ORD + 1)) / 4; e += 64)
        out4[e] = lds4[e];                            // perfectly coalesced
}

extern "C" void kernel_launch(void* const* d_in, const int* in_sizes, int n_in,
                              void* d_out, int out_size, void* d_ws, size_t ws_size,
                              hipStream_t stream) {
    // d_in[0] = excitation (dead in reference), d_in[1] = rc
    const float* rc = (const float*)d_in[1];
    float* out = (float*)d_out;
    hipLaunchKernelGGL(lpc_stepA, dim3((NB * TF) / 64), dim3(64), 0, stream, rc, out);
    hipLaunchKernelGGL(lpc_stepB, dim3((NB * TF) / 64), dim3(64), 0, stream, rc, out);
}